// Round 1
// baseline (259.780 us; speedup 1.0000x reference)
//
#include <hip/hip_runtime.h>
#include <hip/hip_bf16.h>

#define T 8192
#define D 128
#define NSPLIT 4
#define JLEN (T / NSPLIT)   /* 2048 */
#define BN 64
#define NITER (JLEN / BN)   /* 32 */
#define BM 128              /* rows per workgroup */
#define LOG2E 1.44269504088896f

typedef _Float16 half8 __attribute__((ext_vector_type(8)));
typedef float floatx4 __attribute__((ext_vector_type(4)));

// ---------------------------------------------------------------------------
// prep: q16[j][d] = f16(question), qT16[d][j] = f16(question) transposed,
//       cm16[i][d] = f16(context * w_m * log2e)
// grid 256 (128 j-tiles x 2 d-tiles), block 256
// ---------------------------------------------------------------------------
__global__ void prep_kernel(const float* __restrict__ x, const float* __restrict__ kern,
                            _Float16* __restrict__ q16, _Float16* __restrict__ qT16,
                            _Float16* __restrict__ cm16) {
    const float* context  = x;
    const float* question = x + (size_t)T * D;
    const float* wm = kern + 2 * D;
    __shared__ __align__(16) _Float16 tile[64][65];
    int bx = blockIdx.x;
    int jt = bx & 127;
    int dt = bx >> 7;
    int j0 = jt * 64, d0 = dt * 64;
    int t = threadIdx.x;
    for (int k = 0; k < 16; ++k) {
        int idx = t + k * 256;
        int jj = idx >> 6, dd = idx & 63;
        int j = j0 + jj, d = d0 + dd;
        float qv = question[(size_t)j * D + d];
        _Float16 qh = (_Float16)qv;
        q16[(size_t)j * D + d] = qh;
        tile[jj][dd] = qh;
        float cv = context[(size_t)j * D + d] * wm[d] * LOG2E;
        cm16[(size_t)j * D + d] = (_Float16)cv;
    }
    __syncthreads();
    for (int k = 0; k < 16; ++k) {
        int idx = t + k * 256;
        int dd = idx >> 6, jj = idx & 63;
        qT16[(size_t)(d0 + dd) * T + (j0 + jj)] = tile[jj][dd];
    }
}

// ---------------------------------------------------------------------------
// qq2[j] = (question[j] . w_q) * log2e        grid 32, block 256
// ---------------------------------------------------------------------------
__global__ void qq_kernel(const float* __restrict__ x, const float* __restrict__ kern,
                          float* __restrict__ qq2) {
    const float* question = x + (size_t)T * D;
    const float* wq = kern + D;
    int j = blockIdx.x * 256 + threadIdx.x;
    const float4* qrow = (const float4*)(question + (size_t)j * D);
    const float4* w4 = (const float4*)wq;
    float s = 0.f;
    for (int k = 0; k < D / 4; ++k) {
        float4 a = qrow[k], b = w4[k];
        s += a.x * b.x + a.y * b.y + a.z * b.z + a.w * b.w;
    }
    qq2[j] = s * LOG2E;
}

// ---------------------------------------------------------------------------
// flash: Q=cm16, K=q16, V=qT16, bias qqs.  Outputs unnormalized O partials
// (into d_out used as scratch: [sp][i][d] fp32), plus per-(sp,row) m and l.
// grid 256 = 64 row-blocks x 4 j-splits, block 256 (4 waves, 32 rows/wave)
// ---------------------------------------------------------------------------
__global__ __launch_bounds__(256, 2)
void flash_kernel(const _Float16* __restrict__ q16, const _Float16* __restrict__ qT16,
                  const _Float16* __restrict__ cm16, const float* __restrict__ qq2,
                  float* __restrict__ Opart, float* __restrict__ mpart,
                  float* __restrict__ lpart) {
    __shared__ __align__(16) _Float16 Kt[64][136];    // [j][d], +8 pad
    __shared__ __align__(16) _Float16 Vt[128][72];    // [d][j], +8 pad
    __shared__ __align__(16) _Float16 Pt[4][32][72];  // per-wave [i][j], +8 pad
    __shared__ float qqs[64];

    int bx = blockIdx.x;
    int rb = bx >> 2;
    int sp = bx & 3;
    int tid = threadIdx.x;
    int wave = tid >> 6;
    int lane = tid & 63;
    int quad = lane >> 4;
    int l15 = lane & 15;
    int rbase = rb * BM + wave * 32;

    // Q fragments (A-layout: A[m=lane&15][k=quad*8+j]), resident in regs
    half8 qfrag[2][4];
    for (int mt = 0; mt < 2; ++mt)
        for (int ks = 0; ks < 4; ++ks)
            qfrag[mt][ks] = *(const half8*)(cm16 + (size_t)(rbase + mt * 16 + l15) * D
                                            + ks * 32 + quad * 8);

    floatx4 acc[2][8];
    for (int mt = 0; mt < 2; ++mt)
        for (int nt = 0; nt < 8; ++nt)
            for (int r = 0; r < 4; ++r) acc[mt][nt][r] = 0.f;
    float m_run[2][4], l_run[2][4];
    for (int mt = 0; mt < 2; ++mt)
        for (int r = 0; r < 4; ++r) { m_run[mt][r] = -INFINITY; l_run[mt][r] = 0.f; }

    for (int it = 0; it < NITER; ++it) {
        int j0 = sp * JLEN + it * BN;
        // ---- stage K tile [64][128] ----
        for (int k = 0; k < 4; ++k) {
            int idx = tid + k * 256;
            int jr = idx >> 4, c8 = idx & 15;
            *(half8*)&Kt[jr][c8 * 8] = *(const half8*)(q16 + (size_t)(j0 + jr) * D + c8 * 8);
        }
        // ---- stage V^T tile [128][64] ----
        for (int k = 0; k < 4; ++k) {
            int idx = tid + k * 256;
            int dr = idx >> 3, c8 = idx & 7;
            *(half8*)&Vt[dr][c8 * 8] = *(const half8*)(qT16 + (size_t)dr * T + j0 + c8 * 8);
        }
        if (tid < 64) qqs[tid] = qq2[j0 + tid];
        __syncthreads();

        // ---- S = Q K^T  (2 m-tiles x 4 j-tiles, K=128 over 4 ksteps) ----
        floatx4 S[2][4];
        for (int mt = 0; mt < 2; ++mt)
            for (int jt = 0; jt < 4; ++jt)
                for (int r = 0; r < 4; ++r) S[mt][jt][r] = 0.f;
        for (int ks = 0; ks < 4; ++ks)
            for (int jt = 0; jt < 4; ++jt) {
                half8 b = *(const half8*)&Kt[jt * 16 + l15][ks * 32 + quad * 8];
                S[0][jt] = __builtin_amdgcn_mfma_f32_16x16x32_f16(qfrag[0][ks], b, S[0][jt], 0, 0, 0);
                S[1][jt] = __builtin_amdgcn_mfma_f32_16x16x32_f16(qfrag[1][ks], b, S[1][jt], 0, 0, 0);
            }
        float qv[4];
        for (int jt = 0; jt < 4; ++jt) qv[jt] = qqs[jt * 16 + l15];

        // ---- online softmax (logits already in log2 units) ----
        for (int mt = 0; mt < 2; ++mt) {
            float cand[4];
            for (int r = 0; r < 4; ++r) {
                float a0 = S[mt][0][r] + qv[0];
                float a1 = S[mt][1][r] + qv[1];
                float a2 = S[mt][2][r] + qv[2];
                float a3 = S[mt][3][r] + qv[3];
                S[mt][0][r] = a0; S[mt][1][r] = a1; S[mt][2][r] = a2; S[mt][3][r] = a3;
                cand[r] = fmaxf(fmaxf(a0, a1), fmaxf(a2, a3));
            }
            for (int dx = 1; dx <= 8; dx <<= 1)
                for (int r = 0; r < 4; ++r)
                    cand[r] = fmaxf(cand[r], __shfl_xor(cand[r], dx, 64));
            float mnew[4], alpha[4];
            for (int r = 0; r < 4; ++r) {
                mnew[r] = fmaxf(m_run[mt][r], cand[r]);
                alpha[r] = __builtin_amdgcn_exp2f(m_run[mt][r] - mnew[r]);
                m_run[mt][r] = mnew[r];
            }
            for (int r = 0; r < 4; ++r) {
                float ps = 0.f;
                for (int jt = 0; jt < 4; ++jt) {
                    float p = __builtin_amdgcn_exp2f(S[mt][jt][r] - mnew[r]);
                    ps += p;
                    Pt[wave][mt * 16 + quad * 4 + r][jt * 16 + l15] = (_Float16)p;
                }
                l_run[mt][r] = l_run[mt][r] * alpha[r] + ps;
            }
            for (int nt = 0; nt < 8; ++nt)
                for (int r = 0; r < 4; ++r) acc[mt][nt][r] *= alpha[r];
        }

        // ---- O += P V  (per-wave P round-trip through private LDS) ----
        for (int ks = 0; ks < 2; ++ks) {
            half8 a0 = *(const half8*)&Pt[wave][l15][ks * 32 + quad * 8];
            half8 a1 = *(const half8*)&Pt[wave][16 + l15][ks * 32 + quad * 8];
            for (int nt = 0; nt < 8; ++nt) {
                half8 b = *(const half8*)&Vt[nt * 16 + l15][ks * 32 + quad * 8];
                acc[0][nt] = __builtin_amdgcn_mfma_f32_16x16x32_f16(a0, b, acc[0][nt], 0, 0, 0);
                acc[1][nt] = __builtin_amdgcn_mfma_f32_16x16x32_f16(a1, b, acc[1][nt], 0, 0, 0);
            }
        }
        __syncthreads();
    }

    // ---- finalize: reduce l across the 16 lanes of each quad, write out ----
    for (int mt = 0; mt < 2; ++mt) {
        float ls[4];
        for (int r = 0; r < 4; ++r) {
            float s = l_run[mt][r];
            for (int dx = 1; dx <= 8; dx <<= 1) s += __shfl_xor(s, dx, 64);
            ls[r] = s;
        }
        for (int r = 0; r < 4; ++r) {
            int i = rbase + mt * 16 + quad * 4 + r;
            if (l15 == 0) {
                mpart[(size_t)sp * T + i] = m_run[mt][r];
                lpart[(size_t)sp * T + i] = ls[r];
            }
            for (int nt = 0; nt < 8; ++nt)
                Opart[(size_t)sp * T * D + (size_t)i * D + nt * 16 + l15] = acc[mt][nt][r];
        }
    }
}

// ---------------------------------------------------------------------------
// merge 4 split partials -> U_A (fp32), linv[i] = 1/L_i.  grid 512, block 256
// ---------------------------------------------------------------------------
__global__ void merge_kernel(const float* __restrict__ Opart, const float* __restrict__ mpart,
                             const float* __restrict__ lpart, float* __restrict__ U_A,
                             float* __restrict__ linv) {
    int t = threadIdx.x;
    int i = blockIdx.x * 16 + (t >> 4);
    int c = t & 15;
    float mp[NSPLIT], w[NSPLIT];
    float mstar = -INFINITY;
    for (int sp = 0; sp < NSPLIT; ++sp) {
        mp[sp] = mpart[(size_t)sp * T + i];
        mstar = fmaxf(mstar, mp[sp]);
    }
    float L = 0.f;
    for (int sp = 0; sp < NSPLIT; ++sp) {
        w[sp] = __builtin_amdgcn_exp2f(mp[sp] - mstar);
        L += lpart[(size_t)sp * T + i] * w[sp];
    }
    float invL = 1.0f / L;
    int d0 = c * 8;
    float u[8];
    for (int k = 0; k < 8; ++k) u[k] = 0.f;
    for (int sp = 0; sp < NSPLIT; ++sp) {
        const float4* p = (const float4*)(Opart + (size_t)sp * T * D + (size_t)i * D + d0);
        float4 a = p[0], b = p[1];
        u[0] += a.x * w[sp]; u[1] += a.y * w[sp]; u[2] += a.z * w[sp]; u[3] += a.w * w[sp];
        u[4] += b.x * w[sp]; u[5] += b.y * w[sp]; u[6] += b.z * w[sp]; u[7] += b.w * w[sp];
    }
    for (int k = 0; k < 8; ++k) U_A[(size_t)i * D + d0 + k] = u[k] * invL;
    if (c == 0) linv[i] = invL;
}

// ---------------------------------------------------------------------------
// h partials: hpart[b2][d] = sum over 64 rows of context[i][d]*linv[i]
// grid 64, block 256 (two 64-row groups per block)
// ---------------------------------------------------------------------------
__global__ void hsum_part_kernel(const float* __restrict__ x, const float* __restrict__ linv,
                                 float* __restrict__ hpart) {
    const float* context = x;
    int t = threadIdx.x;
    int d = t & 127, g = t >> 7;
    int i0 = blockIdx.x * 128 + g * 64;
    float s = 0.f;
    for (int k = 0; k < 64; ++k)
        s += context[(size_t)(i0 + k) * D + d] * linv[i0 + k];
    hpart[(size_t)(blockIdx.x * 2 + g) * 128 + d] = s;
}

__global__ void hreduce_kernel(const float* __restrict__ hpart, float* __restrict__ h) {
    int d = threadIdx.x;  // 0..127
    float s = 0.f;
    for (int k = 0; k < 128; ++k) s += hpart[(size_t)k * 128 + d];
    h[d] = s;
}

// ---------------------------------------------------------------------------
// assemble G = [ctx, U_A, ctx*U_A, ctx*h]   grid 4096, block 256, float4/thread
// ---------------------------------------------------------------------------
__global__ void assemble_kernel(const float* __restrict__ x, const float* __restrict__ U_A,
                                const float* __restrict__ h, float* __restrict__ out) {
    const float* context = x;
    int gid = blockIdx.x * 256 + threadIdx.x;
    int base = gid * 4;
    int i = base >> 9;
    int c = base & 511;
    int seg = c >> 7, d = c & 127;
    float4 r;
    if (seg == 0) {
        r = *(const float4*)(context + (size_t)i * D + d);
    } else if (seg == 1) {
        r = *(const float4*)(U_A + (size_t)i * D + d);
    } else if (seg == 2) {
        float4 a = *(const float4*)(context + (size_t)i * D + d);
        float4 b = *(const float4*)(U_A + (size_t)i * D + d);
        r = make_float4(a.x * b.x, a.y * b.y, a.z * b.z, a.w * b.w);
    } else {
        float4 a = *(const float4*)(context + (size_t)i * D + d);
        float4 b = *(const float4*)(h + d);
        r = make_float4(a.x * b.x, a.y * b.y, a.z * b.z, a.w * b.w);
    }
    *(float4*)(out + base) = r;
}

// ---------------------------------------------------------------------------
extern "C" void kernel_launch(void* const* d_in, const int* in_sizes, int n_in,
                              void* d_out, int out_size, void* d_ws, size_t ws_size,
                              hipStream_t stream) {
    const float* x = (const float*)d_in[0];
    const float* kern = (const float*)d_in[1];
    float* out = (float*)d_out;

    char* w = (char*)d_ws;
    size_t off = 0;
    _Float16* q16  = (_Float16*)(w + off); off += (size_t)T * D * 2;   // 2 MB
    _Float16* qT16 = (_Float16*)(w + off); off += (size_t)T * D * 2;   // 2 MB
    _Float16* cm16 = (_Float16*)(w + off); off += (size_t)T * D * 2;   // 2 MB
    float* qq2   = (float*)(w + off); off += (size_t)T * 4;            // 32 KB
    float* mpart = (float*)(w + off); off += (size_t)NSPLIT * T * 4;   // 128 KB
    float* lpart = (float*)(w + off); off += (size_t)NSPLIT * T * 4;   // 128 KB
    float* U_A   = (float*)(w + off); off += (size_t)T * D * 4;        // 4 MB
    float* linv  = (float*)(w + off); off += (size_t)T * 4;            // 32 KB
    float* hpart = (float*)(w + off); off += (size_t)128 * 128 * 4;    // 64 KB
    float* h     = (float*)(w + off); off += (size_t)D * 4;

    float* Opart = out;  // d_out doubles as split-partial scratch (4*T*D fp32 = out_size)

    prep_kernel<<<256, 256, 0, stream>>>(x, kern, q16, qT16, cm16);
    qq_kernel<<<32, 256, 0, stream>>>(x, kern, qq2);
    flash_kernel<<<256, 256, 0, stream>>>(q16, qT16, cm16, qq2, Opart, mpart, lpart);
    merge_kernel<<<512, 256, 0, stream>>>(Opart, mpart, lpart, U_A, linv);
    hsum_part_kernel<<<64, 256, 0, stream>>>(x, linv, hpart);
    hreduce_kernel<<<1, 128, 0, stream>>>(hpart, h);
    assemble_kernel<<<4096, 256, 0, stream>>>(x, U_A, h, out);
}

// Round 3
// 141.075 us; speedup vs baseline: 1.8414x; 1.8414x over previous
//
#include <hip/hip_runtime.h>
#include <hip/hip_bf16.h>

#define T 8192
#define D 128
#define NSPLIT 8
#define JLEN (T / NSPLIT)   /* 1024 */
#define BN 64
#define NITER (JLEN / BN)   /* 16 */
#define BM 128              /* rows per workgroup */
#define LOG2E 1.44269504088896f

typedef _Float16 half4_t __attribute__((ext_vector_type(4)));
typedef _Float16 half8_t __attribute__((ext_vector_type(8)));
typedef float floatx4 __attribute__((ext_vector_type(4)));

// ---------------------------------------------------------------------------
// prep: q16[j][d] = f16(question), qT16[d][j] = f16(question) transposed,
//       cm16[i][d] = f16(context * w_m * log2e)
// grid 256 (128 j-tiles x 2 d-tiles), block 256
// ---------------------------------------------------------------------------
__global__ void prep_kernel(const float* __restrict__ x, const float* __restrict__ kern,
                            _Float16* __restrict__ q16, _Float16* __restrict__ qT16,
                            _Float16* __restrict__ cm16) {
    const float* context  = x;
    const float* question = x + (size_t)T * D;
    const float* wm = kern + 2 * D;
    __shared__ __align__(16) _Float16 tile[64][65];
    int bx = blockIdx.x;
    int jt = bx & 127;
    int dt = bx >> 7;
    int j0 = jt * 64, d0 = dt * 64;
    int t = threadIdx.x;
    for (int k = 0; k < 16; ++k) {
        int idx = t + k * 256;
        int jj = idx >> 6, dd = idx & 63;
        int j = j0 + jj, d = d0 + dd;
        float qv = question[(size_t)j * D + d];
        _Float16 qh = (_Float16)qv;
        q16[(size_t)j * D + d] = qh;
        tile[jj][dd] = qh;
        float cv = context[(size_t)j * D + d] * wm[d] * LOG2E;
        cm16[(size_t)j * D + d] = (_Float16)cv;
    }
    __syncthreads();
    for (int k = 0; k < 16; ++k) {
        int idx = t + k * 256;
        int dd = idx >> 6, jj = idx & 63;
        qT16[(size_t)(d0 + dd) * T + (j0 + jj)] = tile[jj][dd];
    }
}

// ---------------------------------------------------------------------------
// qq2[j] = (question[j] . w_q) * log2e        grid 32, block 256
// ---------------------------------------------------------------------------
__global__ void qq_kernel(const float* __restrict__ x, const float* __restrict__ kern,
                          float* __restrict__ qq2) {
    const float* question = x + (size_t)T * D;
    const float* wq = kern + D;
    int j = blockIdx.x * 256 + threadIdx.x;
    const float4* qrow = (const float4*)(question + (size_t)j * D);
    const float4* w4 = (const float4*)wq;
    float s = 0.f;
    for (int k = 0; k < D / 4; ++k) {
        float4 a = qrow[k], b = w4[k];
        s += a.x * b.x + a.y * b.y + a.z * b.z + a.w * b.w;
    }
    qq2[j] = s * LOG2E;
}

// ---------------------------------------------------------------------------
// flash (S^T orientation): St = K (Q*wm)^T so lane holds St[key=4q+r][query=l15].
// P (=exp2(St+bias-m)) in C-layout IS the A-operand layout of 16x16x16 MFMA,
// so PV needs no cross-lane transform. Outputs f16 unnormalized O partials
// into d_out ([sp][i][d]), plus per-(sp,row) m and l.
// grid 512 = 64 row-blocks x 8 j-splits, block 256 (4 waves, 32 rows/wave)
// ---------------------------------------------------------------------------
__global__ __launch_bounds__(256, 2)
void flash_kernel(const _Float16* __restrict__ q16, const _Float16* __restrict__ qT16,
                  const _Float16* __restrict__ cm16, const float* __restrict__ qq2,
                  _Float16* __restrict__ Opart, float* __restrict__ mpart,
                  float* __restrict__ lpart) {
    __shared__ __align__(16) _Float16 Kt[64][144];   // [key][d], stride 144h = 72dw (conflict-free b128)
    __shared__ __align__(16) _Float16 Vt[128][72];   // [d][key], stride 72h
    __shared__ __align__(16) float qqs[JLEN];        // all biases for this split (4KB)

    int bx = blockIdx.x;
    int rb = bx >> 3;
    int sp = bx & 7;
    int tid = threadIdx.x;
    int wave = tid >> 6;
    int lane = tid & 63;
    int quad = lane >> 4;
    int l15 = lane & 15;
    int rbase = rb * BM + wave * 32;

    // stage this split's biases once
    ((float4*)qqs)[tid] = ((const float4*)(qq2 + (size_t)sp * JLEN))[tid];

    // Q fragments (B-operand: B[n=query=l15][k=32ks+8q+j]), resident in regs
    half8_t qfrag[2][4];
    for (int mt = 0; mt < 2; ++mt)
        for (int ks = 0; ks < 4; ++ks)
            qfrag[mt][ks] = *(const half8_t*)(cm16 + (size_t)(rbase + mt * 16 + l15) * D
                                              + ks * 32 + quad * 8);

    floatx4 acc[2][8];
    for (int mt = 0; mt < 2; ++mt)
        for (int nt = 0; nt < 8; ++nt)
            for (int r = 0; r < 4; ++r) acc[mt][nt][r] = 0.f;
    float m_run[2] = {-INFINITY, -INFINITY};
    float l_run[2] = {0.f, 0.f};

    for (int it = 0; it < NITER; ++it) {
        int j0 = sp * JLEN + it * BN;
        // ---- stage K tile [64 keys][128 d] ----
        for (int k = 0; k < 4; ++k) {
            int idx = tid + k * 256;
            int jr = idx >> 4, c8 = idx & 15;
            *(half8_t*)&Kt[jr][c8 * 8] = *(const half8_t*)(q16 + (size_t)(j0 + jr) * D + c8 * 8);
        }
        // ---- stage V^T tile [128 d][64 keys] ----
        for (int k = 0; k < 4; ++k) {
            int idx = tid + k * 256;
            int dr = idx >> 3, c8 = idx & 7;
            *(half8_t*)&Vt[dr][c8 * 8] = *(const half8_t*)(qT16 + (size_t)dr * T + j0 + c8 * 8);
        }
        __syncthreads();

        // ---- St = K Qm^T : St[mt][jt], lane holds key=16jt+4q+r, query=16mt+l15 ----
        floatx4 St[2][4];
        for (int mt = 0; mt < 2; ++mt)
            for (int jt = 0; jt < 4; ++jt)
                for (int r = 0; r < 4; ++r) St[mt][jt][r] = 0.f;
        for (int ks = 0; ks < 4; ++ks)
            for (int jt = 0; jt < 4; ++jt) {
                half8_t a = *(const half8_t*)&Kt[jt * 16 + l15][ks * 32 + quad * 8];
                St[0][jt] = __builtin_amdgcn_mfma_f32_16x16x32_f16(a, qfrag[0][ks], St[0][jt], 0, 0, 0);
                St[1][jt] = __builtin_amdgcn_mfma_f32_16x16x32_f16(a, qfrag[1][ks], St[1][jt], 0, 0, 0);
            }

        // ---- per-key bias (float4 along r) ----
        float4 bias[4];
        for (int jt = 0; jt < 4; ++jt)
            bias[jt] = *(const float4*)&qqs[it * 64 + jt * 16 + quad * 4];
        for (int mt = 0; mt < 2; ++mt) {
            St[mt][0][0] += bias[0].x; St[mt][0][1] += bias[0].y; St[mt][0][2] += bias[0].z; St[mt][0][3] += bias[0].w;
            St[mt][1][0] += bias[1].x; St[mt][1][1] += bias[1].y; St[mt][1][2] += bias[1].z; St[mt][1][3] += bias[1].w;
            St[mt][2][0] += bias[2].x; St[mt][2][1] += bias[2].y; St[mt][2][2] += bias[2].z; St[mt][2][3] += bias[2].w;
            St[mt][3][0] += bias[3].x; St[mt][3][1] += bias[3].y; St[mt][3][2] += bias[3].z; St[mt][3][3] += bias[3].w;
        }

        // ---- online softmax + PV ----
        half4_t apv[2][4];
        float alpha[2];
        for (int mt = 0; mt < 2; ++mt) {
            float mx = St[mt][0][0];
            for (int jt = 0; jt < 4; ++jt)
                for (int r = 0; r < 4; ++r) mx = fmaxf(mx, St[mt][jt][r]);
            mx = fmaxf(mx, __shfl_xor(mx, 16));
            mx = fmaxf(mx, __shfl_xor(mx, 32));
            float mnew = fmaxf(m_run[mt], mx);
            alpha[mt] = __builtin_amdgcn_exp2f(m_run[mt] - mnew);
            m_run[mt] = mnew;
            float ps = 0.f;
            for (int jt = 0; jt < 4; ++jt) {
                float p0 = __builtin_amdgcn_exp2f(St[mt][jt][0] - mnew);
                float p1 = __builtin_amdgcn_exp2f(St[mt][jt][1] - mnew);
                float p2 = __builtin_amdgcn_exp2f(St[mt][jt][2] - mnew);
                float p3 = __builtin_amdgcn_exp2f(St[mt][jt][3] - mnew);
                ps += (p0 + p1) + (p2 + p3);
                apv[mt][jt][0] = (_Float16)p0;
                apv[mt][jt][1] = (_Float16)p1;
                apv[mt][jt][2] = (_Float16)p2;
                apv[mt][jt][3] = (_Float16)p3;
            }
            ps += __shfl_xor(ps, 16);
            ps += __shfl_xor(ps, 32);
            l_run[mt] = l_run[mt] * alpha[mt] + ps;
        }
        // rescale acc by alpha transposed into (quad,r) query domain
        for (int mt = 0; mt < 2; ++mt) {
            float aT[4];
            for (int r = 0; r < 4; ++r)
                aT[r] = __shfl(alpha[mt], quad * 4 + r);
            for (int nt = 0; nt < 8; ++nt)
                for (int r = 0; r < 4; ++r) acc[mt][nt][r] *= aT[r];
        }

        // ---- O += P V via 16x16x16 (A=P already in-layout) ----
        for (int jt = 0; jt < 4; ++jt)
            for (int nt = 0; nt < 8; ++nt) {
                half4_t b = *(const half4_t*)&Vt[nt * 16 + l15][jt * 16 + quad * 4];
                acc[0][nt] = __builtin_amdgcn_mfma_f32_16x16x16f16(apv[0][jt], b, acc[0][nt], 0, 0, 0);
                acc[1][nt] = __builtin_amdgcn_mfma_f32_16x16x16f16(apv[1][jt], b, acc[1][nt], 0, 0, 0);
            }
        __syncthreads();
    }

    // ---- finalize ----
    for (int mt = 0; mt < 2; ++mt) {
        if (quad == 0) {
            int iq = rbase + mt * 16 + l15;
            mpart[(size_t)sp * T + iq] = m_run[mt];
            lpart[(size_t)sp * T + iq] = l_run[mt];
        }
        int i = rbase + mt * 16 + quad * 4;
        for (int nt = 0; nt < 8; ++nt)
            for (int r = 0; r < 4; ++r)
                Opart[((size_t)sp * T + (i + r)) * D + nt * 16 + l15] = (_Float16)acc[mt][nt][r];
    }
}

// ---------------------------------------------------------------------------
// merge 8 f16 split partials -> U_A (fp32), linv[i] = 1/L_i.  grid 512, block 256
// ---------------------------------------------------------------------------
__global__ void merge_kernel(const _Float16* __restrict__ Opart, const float* __restrict__ mpart,
                             const float* __restrict__ lpart, float* __restrict__ U_A,
                             float* __restrict__ linv) {
    int t = threadIdx.x;
    int i = blockIdx.x * 16 + (t >> 4);
    int c = t & 15;
    float mp[NSPLIT], w[NSPLIT];
    float mstar = -INFINITY;
    for (int sp = 0; sp < NSPLIT; ++sp) {
        mp[sp] = mpart[(size_t)sp * T + i];
        mstar = fmaxf(mstar, mp[sp]);
    }
    float L = 0.f;
    for (int sp = 0; sp < NSPLIT; ++sp) {
        w[sp] = __builtin_amdgcn_exp2f(mp[sp] - mstar);
        L += lpart[(size_t)sp * T + i] * w[sp];
    }
    float invL = 1.0f / L;
    int d0 = c * 8;
    float u[8];
    for (int k = 0; k < 8; ++k) u[k] = 0.f;
    for (int sp = 0; sp < NSPLIT; ++sp) {
        half8_t o = *(const half8_t*)(Opart + ((size_t)sp * T + i) * D + d0);
        for (int k = 0; k < 8; ++k) u[k] += (float)o[k] * w[sp];
    }
    for (int k = 0; k < 8; ++k) U_A[(size_t)i * D + d0 + k] = u[k] * invL;
    if (c == 0) linv[i] = invL;
}

// ---------------------------------------------------------------------------
// h partials: hpart[b2][d] = sum over 64 rows of context[i][d]*linv[i]
// grid 64, block 256 (two 64-row groups per block)
// ---------------------------------------------------------------------------
__global__ void hsum_part_kernel(const float* __restrict__ x, const float* __restrict__ linv,
                                 float* __restrict__ hpart) {
    const float* context = x;
    int t = threadIdx.x;
    int d = t & 127, g = t >> 7;
    int i0 = blockIdx.x * 128 + g * 64;
    float s = 0.f;
    for (int k = 0; k < 64; ++k)
        s += context[(size_t)(i0 + k) * D + d] * linv[i0 + k];
    hpart[(size_t)(blockIdx.x * 2 + g) * 128 + d] = s;
}

__global__ void hreduce_kernel(const float* __restrict__ hpart, float* __restrict__ h) {
    int d = threadIdx.x;  // 0..127
    float s = 0.f;
    for (int k = 0; k < 128; ++k) s += hpart[(size_t)k * 128 + d];
    h[d] = s;
}

// ---------------------------------------------------------------------------
// assemble G = [ctx, U_A, ctx*U_A, ctx*h]   grid 4096, block 256, float4/thread
// ---------------------------------------------------------------------------
__global__ void assemble_kernel(const float* __restrict__ x, const float* __restrict__ U_A,
                                const float* __restrict__ h, float* __restrict__ out) {
    const float* context = x;
    int gid = blockIdx.x * 256 + threadIdx.x;
    int base = gid * 4;
    int i = base >> 9;
    int c = base & 511;
    int seg = c >> 7, d = c & 127;
    float4 r;
    if (seg == 0) {
        r = *(const float4*)(context + (size_t)i * D + d);
    } else if (seg == 1) {
        r = *(const float4*)(U_A + (size_t)i * D + d);
    } else if (seg == 2) {
        float4 a = *(const float4*)(context + (size_t)i * D + d);
        float4 b = *(const float4*)(U_A + (size_t)i * D + d);
        r = make_float4(a.x * b.x, a.y * b.y, a.z * b.z, a.w * b.w);
    } else {
        float4 a = *(const float4*)(context + (size_t)i * D + d);
        float4 b = *(const float4*)(h + d);
        r = make_float4(a.x * b.x, a.y * b.y, a.z * b.z, a.w * b.w);
    }
    *(float4*)(out + base) = r;
}

// ---------------------------------------------------------------------------
extern "C" void kernel_launch(void* const* d_in, const int* in_sizes, int n_in,
                              void* d_out, int out_size, void* d_ws, size_t ws_size,
                              hipStream_t stream) {
    const float* x = (const float*)d_in[0];
    const float* kern = (const float*)d_in[1];
    float* out = (float*)d_out;

    char* w = (char*)d_ws;
    size_t off = 0;
    _Float16* q16  = (_Float16*)(w + off); off += (size_t)T * D * 2;   // 2 MB
    _Float16* qT16 = (_Float16*)(w + off); off += (size_t)T * D * 2;   // 2 MB
    _Float16* cm16 = (_Float16*)(w + off); off += (size_t)T * D * 2;   // 2 MB
    float* qq2   = (float*)(w + off); off += (size_t)T * 4;            // 32 KB
    float* mpart = (float*)(w + off); off += (size_t)NSPLIT * T * 4;   // 256 KB
    float* lpart = (float*)(w + off); off += (size_t)NSPLIT * T * 4;   // 256 KB
    float* U_A   = (float*)(w + off); off += (size_t)T * D * 4;        // 4 MB
    float* linv  = (float*)(w + off); off += (size_t)T * 4;            // 32 KB
    float* hpart = (float*)(w + off); off += (size_t)128 * 128 * 4;    // 64 KB
    float* h     = (float*)(w + off); off += (size_t)D * 4;

    // d_out doubles as f16 split-partial scratch: 8 * T * D * 2B = 16 MB = out bytes
    _Float16* Opart = (_Float16*)d_out;

    prep_kernel<<<256, 256, 0, stream>>>(x, kern, q16, qT16, cm16);
    qq_kernel<<<32, 256, 0, stream>>>(x, kern, qq2);
    flash_kernel<<<512, 256, 0, stream>>>(q16, qT16, cm16, qq2, Opart, mpart, lpart);
    merge_kernel<<<512, 256, 0, stream>>>(Opart, mpart, lpart, U_A, linv);
    hsum_part_kernel<<<64, 256, 0, stream>>>(x, linv, hpart);
    hreduce_kernel<<<1, 128, 0, stream>>>(hpart, h);
    assemble_kernel<<<4096, 256, 0, stream>>>(x, U_A, h, out);
}

// Round 4
// 138.538 us; speedup vs baseline: 1.8752x; 1.0183x over previous
//
#include <hip/hip_runtime.h>
#include <hip/hip_bf16.h>

#define T 8192
#define D 128
#define NSPLIT 8
#define JLEN (T / NSPLIT)   /* 1024 */
#define BN 64
#define NITER (JLEN / BN)   /* 16 */
#define BM 128              /* rows per workgroup */
#define LOG2E 1.44269504088896f

typedef _Float16 half4_t __attribute__((ext_vector_type(4)));
typedef _Float16 half8_t __attribute__((ext_vector_type(8)));
typedef float floatx4 __attribute__((ext_vector_type(4)));

// ---------------------------------------------------------------------------
// prep (fused + qq + h-zero): q16 = f16(question), qT16 = transpose,
// cm16 = f16(context * w_m * log2e), qq2[j] = (question[j].w_q)*log2e, h = 0.
// grid 128 (64 rows each, full 128 cols), block 256
// ---------------------------------------------------------------------------
__global__ void prep_kernel(const float* __restrict__ x, const float* __restrict__ kern,
                            _Float16* __restrict__ q16, _Float16* __restrict__ qT16,
                            _Float16* __restrict__ cm16, float* __restrict__ qq2,
                            float* __restrict__ h) {
    const float* context  = x;
    const float* question = x + (size_t)T * D;
    const float* wq = kern + D;
    const float* wm = kern + 2 * D;
    __shared__ __align__(16) _Float16 tile[64][136];
    __shared__ float red[64][4];
    int j0 = blockIdx.x * 64;
    int t = threadIdx.x;
    int jj = t >> 2, dseg = t & 3;   // row within block, 32-col segment
    const float4* qrow = (const float4*)(question + (size_t)(j0 + jj) * D + dseg * 32);
    const float4* crow = (const float4*)(context  + (size_t)(j0 + jj) * D + dseg * 32);
    const float4* wq4  = (const float4*)(wq + dseg * 32);
    const float4* wm4  = (const float4*)(wm + dseg * 32);
    float s = 0.f;
    for (int c = 0; c < 4; ++c) {    // 8 floats per step
        float4 q0 = qrow[c * 2], q1 = qrow[c * 2 + 1];
        float4 w0 = wq4[c * 2], w1 = wq4[c * 2 + 1];
        s += q0.x * w0.x + q0.y * w0.y + q0.z * w0.z + q0.w * w0.w
           + q1.x * w1.x + q1.y * w1.y + q1.z * w1.z + q1.w * w1.w;
        half8_t qh;
        qh[0] = (_Float16)q0.x; qh[1] = (_Float16)q0.y; qh[2] = (_Float16)q0.z; qh[3] = (_Float16)q0.w;
        qh[4] = (_Float16)q1.x; qh[5] = (_Float16)q1.y; qh[6] = (_Float16)q1.z; qh[7] = (_Float16)q1.w;
        *(half8_t*)(q16 + (size_t)(j0 + jj) * D + dseg * 32 + c * 8) = qh;
        *(half8_t*)&tile[jj][dseg * 32 + c * 8] = qh;
        float4 c0 = crow[c * 2], c1 = crow[c * 2 + 1];
        float4 m0 = wm4[c * 2], m1 = wm4[c * 2 + 1];
        half8_t ch;
        ch[0] = (_Float16)(c0.x * m0.x * LOG2E); ch[1] = (_Float16)(c0.y * m0.y * LOG2E);
        ch[2] = (_Float16)(c0.z * m0.z * LOG2E); ch[3] = (_Float16)(c0.w * m0.w * LOG2E);
        ch[4] = (_Float16)(c1.x * m1.x * LOG2E); ch[5] = (_Float16)(c1.y * m1.y * LOG2E);
        ch[6] = (_Float16)(c1.z * m1.z * LOG2E); ch[7] = (_Float16)(c1.w * m1.w * LOG2E);
        *(half8_t*)(cm16 + (size_t)(j0 + jj) * D + dseg * 32 + c * 8) = ch;
    }
    red[jj][dseg] = s;
    if (blockIdx.x == 0 && t < 128) h[t] = 0.f;
    __syncthreads();
    if (t < 64)
        qq2[j0 + t] = (red[t][0] + red[t][1] + red[t][2] + red[t][3]) * LOG2E;
    // transpose out: qT16[d][j0+..], half8 along j
    for (int k = 0; k < 4; ++k) {
        int ch = t + k * 256;          // 0..1023
        int d = ch >> 3;               // 0..127
        int jo = (ch & 7) * 8;
        half8_t v;
        for (int s2 = 0; s2 < 8; ++s2) v[s2] = tile[jo + s2][d];
        *(half8_t*)(qT16 + (size_t)d * T + j0 + jo) = v;
    }
}

// ---------------------------------------------------------------------------
// flash (S^T orientation, register-prefetch double buffer): St = K (Q*wm)^T;
// P's C-layout IS the A-operand layout of 16x16x16 MFMA. f16 O partials into
// d_out ([sp][i][d]), per-(sp,row) m and l.
// grid 512 = 64 row-blocks x 8 j-splits, block 256 (4 waves, 32 rows/wave)
// ---------------------------------------------------------------------------
__global__ __launch_bounds__(256, 2)
void flash_kernel(const _Float16* __restrict__ q16, const _Float16* __restrict__ qT16,
                  const _Float16* __restrict__ cm16, const float* __restrict__ qq2,
                  _Float16* __restrict__ Opart, float* __restrict__ mpart,
                  float* __restrict__ lpart) {
    __shared__ __align__(16) _Float16 Kt[64][144];   // [key][d], stride 144h
    __shared__ __align__(16) _Float16 Vt[128][72];   // [d][key], stride 72h
    __shared__ __align__(16) float qqs[JLEN];        // biases for this split (4KB)

    int bx = blockIdx.x;
    int rb = bx >> 3;
    int sp = bx & 7;
    int tid = threadIdx.x;
    int wave = tid >> 6;
    int lane = tid & 63;
    int quad = lane >> 4;
    int l15 = lane & 15;
    int rbase = rb * BM + wave * 32;

    ((float4*)qqs)[tid] = ((const float4*)(qq2 + (size_t)sp * JLEN))[tid];

    half8_t qfrag[2][4];
    for (int mt = 0; mt < 2; ++mt)
        for (int ks = 0; ks < 4; ++ks)
            qfrag[mt][ks] = *(const half8_t*)(cm16 + (size_t)(rbase + mt * 16 + l15) * D
                                              + ks * 32 + quad * 8);

    floatx4 acc[2][8];
    for (int mt = 0; mt < 2; ++mt)
        for (int nt = 0; nt < 8; ++nt)
            for (int r = 0; r < 4; ++r) acc[mt][nt][r] = 0.f;
    float m_run[2] = {-INFINITY, -INFINITY};
    float l_run[2] = {0.f, 0.f};

    // prefetch iter 0 tiles into registers
    half8_t kreg[4], vreg[4];
    {
        int j0 = sp * JLEN;
        for (int k = 0; k < 4; ++k) {
            int idx = tid + k * 256;
            kreg[k] = *(const half8_t*)(q16 + (size_t)(j0 + (idx >> 4)) * D + (idx & 15) * 8);
        }
        for (int k = 0; k < 4; ++k) {
            int idx = tid + k * 256;
            vreg[k] = *(const half8_t*)(qT16 + (size_t)(idx >> 3) * T + j0 + (idx & 7) * 8);
        }
    }

    for (int it = 0; it < NITER; ++it) {
        // ---- commit prefetched tiles to LDS ----
        for (int k = 0; k < 4; ++k) {
            int idx = tid + k * 256;
            *(half8_t*)&Kt[idx >> 4][(idx & 15) * 8] = kreg[k];
        }
        for (int k = 0; k < 4; ++k) {
            int idx = tid + k * 256;
            *(half8_t*)&Vt[idx >> 3][(idx & 7) * 8] = vreg[k];
        }
        __syncthreads();

        // ---- issue next iteration's global loads (latency overlaps compute) ----
        if (it + 1 < NITER) {
            int j0n = sp * JLEN + (it + 1) * BN;
            for (int k = 0; k < 4; ++k) {
                int idx = tid + k * 256;
                kreg[k] = *(const half8_t*)(q16 + (size_t)(j0n + (idx >> 4)) * D + (idx & 15) * 8);
            }
            for (int k = 0; k < 4; ++k) {
                int idx = tid + k * 256;
                vreg[k] = *(const half8_t*)(qT16 + (size_t)(idx >> 3) * T + j0n + (idx & 7) * 8);
            }
        }

        // ---- St = K Qm^T ----
        floatx4 St[2][4];
        for (int mt = 0; mt < 2; ++mt)
            for (int jt = 0; jt < 4; ++jt)
                for (int r = 0; r < 4; ++r) St[mt][jt][r] = 0.f;
        for (int ks = 0; ks < 4; ++ks)
            for (int jt = 0; jt < 4; ++jt) {
                half8_t a = *(const half8_t*)&Kt[jt * 16 + l15][ks * 32 + quad * 8];
                St[0][jt] = __builtin_amdgcn_mfma_f32_16x16x32_f16(a, qfrag[0][ks], St[0][jt], 0, 0, 0);
                St[1][jt] = __builtin_amdgcn_mfma_f32_16x16x32_f16(a, qfrag[1][ks], St[1][jt], 0, 0, 0);
            }

        // ---- per-key bias ----
        float4 bias[4];
        for (int jt = 0; jt < 4; ++jt)
            bias[jt] = *(const float4*)&qqs[it * 64 + jt * 16 + quad * 4];
        for (int mt = 0; mt < 2; ++mt) {
            St[mt][0][0] += bias[0].x; St[mt][0][1] += bias[0].y; St[mt][0][2] += bias[0].z; St[mt][0][3] += bias[0].w;
            St[mt][1][0] += bias[1].x; St[mt][1][1] += bias[1].y; St[mt][1][2] += bias[1].z; St[mt][1][3] += bias[1].w;
            St[mt][2][0] += bias[2].x; St[mt][2][1] += bias[2].y; St[mt][2][2] += bias[2].z; St[mt][2][3] += bias[2].w;
            St[mt][3][0] += bias[3].x; St[mt][3][1] += bias[3].y; St[mt][3][2] += bias[3].z; St[mt][3][3] += bias[3].w;
        }

        // ---- online softmax ----
        half4_t apv[2][4];
        float alpha[2];
        for (int mt = 0; mt < 2; ++mt) {
            float mx = St[mt][0][0];
            for (int jt = 0; jt < 4; ++jt)
                for (int r = 0; r < 4; ++r) mx = fmaxf(mx, St[mt][jt][r]);
            mx = fmaxf(mx, __shfl_xor(mx, 16));
            mx = fmaxf(mx, __shfl_xor(mx, 32));
            float mnew = fmaxf(m_run[mt], mx);
            alpha[mt] = __builtin_amdgcn_exp2f(m_run[mt] - mnew);
            m_run[mt] = mnew;
            float ps = 0.f;
            for (int jt = 0; jt < 4; ++jt) {
                float p0 = __builtin_amdgcn_exp2f(St[mt][jt][0] - mnew);
                float p1 = __builtin_amdgcn_exp2f(St[mt][jt][1] - mnew);
                float p2 = __builtin_amdgcn_exp2f(St[mt][jt][2] - mnew);
                float p3 = __builtin_amdgcn_exp2f(St[mt][jt][3] - mnew);
                ps += (p0 + p1) + (p2 + p3);
                apv[mt][jt][0] = (_Float16)p0;
                apv[mt][jt][1] = (_Float16)p1;
                apv[mt][jt][2] = (_Float16)p2;
                apv[mt][jt][3] = (_Float16)p3;
            }
            ps += __shfl_xor(ps, 16);
            ps += __shfl_xor(ps, 32);
            l_run[mt] = l_run[mt] * alpha[mt] + ps;
        }
        for (int mt = 0; mt < 2; ++mt) {
            float aT[4];
            for (int r = 0; r < 4; ++r)
                aT[r] = __shfl(alpha[mt], quad * 4 + r);
            for (int nt = 0; nt < 8; ++nt)
                for (int r = 0; r < 4; ++r) acc[mt][nt][r] *= aT[r];
        }

        // ---- O += P V via 16x16x16 (A=P already in-layout) ----
        for (int jt = 0; jt < 4; ++jt)
            for (int nt = 0; nt < 8; ++nt) {
                half4_t b = *(const half4_t*)&Vt[nt * 16 + l15][jt * 16 + quad * 4];
                acc[0][nt] = __builtin_amdgcn_mfma_f32_16x16x16f16(apv[0][jt], b, acc[0][nt], 0, 0, 0);
                acc[1][nt] = __builtin_amdgcn_mfma_f32_16x16x16f16(apv[1][jt], b, acc[1][nt], 0, 0, 0);
            }
        __syncthreads();
    }

    // ---- finalize ----
    for (int mt = 0; mt < 2; ++mt) {
        if (quad == 0) {
            int iq = rbase + mt * 16 + l15;
            mpart[(size_t)sp * T + iq] = m_run[mt];
            lpart[(size_t)sp * T + iq] = l_run[mt];
        }
        int i = rbase + mt * 16 + quad * 4;
        for (int nt = 0; nt < 8; ++nt)
            for (int r = 0; r < 4; ++r)
                Opart[((size_t)sp * T + (i + r)) * D + nt * 16 + l15] = (_Float16)acc[mt][nt][r];
    }
}

// ---------------------------------------------------------------------------
// merge (fused + h): 8 f16 split partials -> U_A (fp32); per-block h partial
// (16 rows) reduced in LDS then atomicAdd into h[128]. grid 512, block 256
// ---------------------------------------------------------------------------
__global__ void merge_kernel(const _Float16* __restrict__ Opart, const float* __restrict__ mpart,
                             const float* __restrict__ lpart, const float* __restrict__ x,
                             float* __restrict__ U_A, float* __restrict__ h) {
    __shared__ float hs[256][8];
    const float* context = x;
    int t = threadIdx.x;
    int i = blockIdx.x * 16 + (t >> 4);
    int c = t & 15;
    float mp[NSPLIT], w[NSPLIT];
    float mstar = -INFINITY;
    for (int sp = 0; sp < NSPLIT; ++sp) {
        mp[sp] = mpart[(size_t)sp * T + i];
        mstar = fmaxf(mstar, mp[sp]);
    }
    float L = 0.f;
    for (int sp = 0; sp < NSPLIT; ++sp) {
        w[sp] = __builtin_amdgcn_exp2f(mp[sp] - mstar);
        L += lpart[(size_t)sp * T + i] * w[sp];
    }
    float invL = 1.0f / L;
    int d0 = c * 8;
    float u[8];
    for (int k = 0; k < 8; ++k) u[k] = 0.f;
    for (int sp = 0; sp < NSPLIT; ++sp) {
        half8_t o = *(const half8_t*)(Opart + ((size_t)sp * T + i) * D + d0);
        for (int k = 0; k < 8; ++k) u[k] += (float)o[k] * w[sp];
    }
    for (int k = 0; k < 8; ++k) U_A[(size_t)i * D + d0 + k] = u[k] * invL;
    // h partial: ctx[i][d0..d0+8) * invL
    float4 c0 = *(const float4*)(context + (size_t)i * D + d0);
    float4 c1 = *(const float4*)(context + (size_t)i * D + d0 + 4);
    hs[t][0] = c0.x * invL; hs[t][1] = c0.y * invL; hs[t][2] = c0.z * invL; hs[t][3] = c0.w * invL;
    hs[t][4] = c1.x * invL; hs[t][5] = c1.y * invL; hs[t][6] = c1.z * invL; hs[t][7] = c1.w * invL;
    __syncthreads();
    if (t < 128) {
        int d = t, cc = d >> 3, k = d & 7;
        float s = 0.f;
        for (int r = 0; r < 16; ++r) s += hs[r * 16 + cc][k];
        atomicAdd(&h[d], s);
    }
}

// ---------------------------------------------------------------------------
// assemble G = [ctx, U_A, ctx*U_A, ctx*h]   grid 4096, block 256, float4/thread
// ---------------------------------------------------------------------------
__global__ void assemble_kernel(const float* __restrict__ x, const float* __restrict__ U_A,
                                const float* __restrict__ h, float* __restrict__ out) {
    const float* context = x;
    int gid = blockIdx.x * 256 + threadIdx.x;
    int base = gid * 4;
    int i = base >> 9;
    int c = base & 511;
    int seg = c >> 7, d = c & 127;
    float4 r;
    if (seg == 0) {
        r = *(const float4*)(context + (size_t)i * D + d);
    } else if (seg == 1) {
        r = *(const float4*)(U_A + (size_t)i * D + d);
    } else if (seg == 2) {
        float4 a = *(const float4*)(context + (size_t)i * D + d);
        float4 b = *(const float4*)(U_A + (size_t)i * D + d);
        r = make_float4(a.x * b.x, a.y * b.y, a.z * b.z, a.w * b.w);
    } else {
        float4 a = *(const float4*)(context + (size_t)i * D + d);
        float4 b = *(const float4*)(h + d);
        r = make_float4(a.x * b.x, a.y * b.y, a.z * b.z, a.w * b.w);
    }
    *(float4*)(out + base) = r;
}

// ---------------------------------------------------------------------------
extern "C" void kernel_launch(void* const* d_in, const int* in_sizes, int n_in,
                              void* d_out, int out_size, void* d_ws, size_t ws_size,
                              hipStream_t stream) {
    const float* x = (const float*)d_in[0];
    const float* kern = (const float*)d_in[1];
    float* out = (float*)d_out;

    char* w = (char*)d_ws;
    size_t off = 0;
    _Float16* q16  = (_Float16*)(w + off); off += (size_t)T * D * 2;   // 2 MB
    _Float16* qT16 = (_Float16*)(w + off); off += (size_t)T * D * 2;   // 2 MB
    _Float16* cm16 = (_Float16*)(w + off); off += (size_t)T * D * 2;   // 2 MB
    float* qq2   = (float*)(w + off); off += (size_t)T * 4;            // 32 KB
    float* mpart = (float*)(w + off); off += (size_t)NSPLIT * T * 4;   // 256 KB
    float* lpart = (float*)(w + off); off += (size_t)NSPLIT * T * 4;   // 256 KB
    float* U_A   = (float*)(w + off); off += (size_t)T * D * 4;        // 4 MB
    float* h     = (float*)(w + off); off += (size_t)D * 4;

    // d_out doubles as f16 split-partial scratch: 8 * T * D * 2B = 16 MB
    _Float16* Opart = (_Float16*)d_out;

    prep_kernel<<<128, 256, 0, stream>>>(x, kern, q16, qT16, cm16, qq2, h);
    flash_kernel<<<512, 256, 0, stream>>>(q16, qT16, cm16, qq2, Opart, mpart, lpart);
    merge_kernel<<<512, 256, 0, stream>>>(Opart, mpart, lpart, x, U_A, h);
    assemble_kernel<<<4096, 256, 0, stream>>>(x, U_A, h, out);
}

// Round 5
// 136.156 us; speedup vs baseline: 1.9080x; 1.0175x over previous
//
#include <hip/hip_runtime.h>
#include <hip/hip_bf16.h>

#define T 8192
#define D 128
#define NSPLIT 8
#define JLEN (T / NSPLIT)   /* 1024 */
#define BN 64
#define NITER (JLEN / BN)   /* 16 */
#define BM 128              /* rows per workgroup */
#define LOG2E 1.44269504088896f

typedef _Float16 half4_t __attribute__((ext_vector_type(4)));
typedef _Float16 half8_t __attribute__((ext_vector_type(8)));
typedef float floatx4 __attribute__((ext_vector_type(4)));

// ---------------------------------------------------------------------------
// prep: q16 = f16(question), qT16 = transpose, cm16 = f16(ctx*w_m*log2e),
// qq2[j] = (question[j].w_q)*log2e.  Fully coalesced float4 lanes.
// grid 256 (32 rows/block), block 256
// ---------------------------------------------------------------------------
__global__ void prep_kernel(const float* __restrict__ x, const float* __restrict__ kern,
                            _Float16* __restrict__ q16, _Float16* __restrict__ qT16,
                            _Float16* __restrict__ cm16, float* __restrict__ qq2) {
    const float* context  = x;
    const float* question = x + (size_t)T * D;
    const float* wq = kern + D;
    const float* wm = kern + 2 * D;
    __shared__ __align__(16) _Float16 tile[32][136];
    int j0 = blockIdx.x * 32;
    int t = threadIdx.x;
    int c4 = t & 31;       // float4 index within row (0..31)
    int rsub = t >> 5;     // 0..7
    float4 wqv = ((const float4*)wq)[c4];
    float4 wmv = ((const float4*)wm)[c4];
    for (int p = 0; p < 4; ++p) {
        int row = p * 8 + rsub;
        float4 q = ((const float4*)(question + (size_t)(j0 + row) * D))[c4];
        float4 c = ((const float4*)(context  + (size_t)(j0 + row) * D))[c4];
        half4_t qh;
        qh[0] = (_Float16)q.x; qh[1] = (_Float16)q.y; qh[2] = (_Float16)q.z; qh[3] = (_Float16)q.w;
        *(half4_t*)(q16 + (size_t)(j0 + row) * D + c4 * 4) = qh;
        *(half4_t*)&tile[row][c4 * 4] = qh;
        half4_t ch;
        ch[0] = (_Float16)(c.x * wmv.x * LOG2E); ch[1] = (_Float16)(c.y * wmv.y * LOG2E);
        ch[2] = (_Float16)(c.z * wmv.z * LOG2E); ch[3] = (_Float16)(c.w * wmv.w * LOG2E);
        *(half4_t*)(cm16 + (size_t)(j0 + row) * D + c4 * 4) = ch;
        float s = q.x * wqv.x + q.y * wqv.y + q.z * wqv.z + q.w * wqv.w;
        for (int dx = 1; dx <= 16; dx <<= 1) s += __shfl_xor(s, dx);
        if (c4 == 0) qq2[j0 + row] = s * LOG2E;
    }
    __syncthreads();
    for (int p = 0; p < 2; ++p) {
        int chunk = t + p * 256;
        int d = chunk >> 2, jo = (chunk & 3) * 8;
        half8_t v;
        for (int s2 = 0; s2 < 8; ++s2) v[s2] = tile[jo + s2][d];
        *(half8_t*)(qT16 + (size_t)d * T + j0 + jo) = v;
    }
}

// ---------------------------------------------------------------------------
// flash (S^T orientation, single-barrier LDS double buffer):
// St = K (Q*wm)^T; P's C-layout IS the A-operand layout of 16x16x16 MFMA.
// Vt stored in interleaved-pair layout: phys p = pr*32 + quad*8 + h*4 + r
// holds logical key (2pr+h)*16 + quad*4 + r, so PV b-operands are b128 reads.
// grid 512 = 64 row-blocks x 8 j-splits, block 256 (4 waves, 32 rows/wave)
// ---------------------------------------------------------------------------
__global__ __launch_bounds__(256, 2)
void flash_kernel(const _Float16* __restrict__ q16, const _Float16* __restrict__ qT16,
                  const _Float16* __restrict__ cm16, const float* __restrict__ qq2,
                  _Float16* __restrict__ Opart, float* __restrict__ mpart,
                  float* __restrict__ lpart) {
    __shared__ __align__(16) _Float16 Kt[2][64][144];   // [buf][key][d]
    __shared__ __align__(16) _Float16 Vt[2][128][72];   // [buf][d][phys key]
    __shared__ __align__(16) float qqs[JLEN];

    int bx = blockIdx.x;
    int rb = bx >> 3;
    int sp = bx & 7;
    int tid = threadIdx.x;
    int wave = tid >> 6;
    int lane = tid & 63;
    int quad = lane >> 4;
    int l15 = lane & 15;
    int rbase = rb * BM + wave * 32;

    ((float4*)qqs)[tid] = ((const float4*)(qq2 + (size_t)sp * JLEN))[tid];

    half8_t qfrag[2][4];
    for (int mt = 0; mt < 2; ++mt)
        for (int ks = 0; ks < 4; ++ks)
            qfrag[mt][ks] = *(const half8_t*)(cm16 + (size_t)(rbase + mt * 16 + l15) * D
                                              + ks * 32 + quad * 8);

    floatx4 acc[2][8];
    for (int mt = 0; mt < 2; ++mt)
        for (int nt = 0; nt < 8; ++nt)
            for (int r = 0; r < 4; ++r) acc[mt][nt][r] = 0.f;
    float m_run[2] = {-INFINITY, -INFINITY};
    float l_run[2] = {0.f, 0.f};

    half8_t kreg[4];
    half4_t vlo[4], vhi[4];

    // ---- load iter 0 tiles into registers ----
    {
        int j0 = sp * JLEN;
        for (int k = 0; k < 4; ++k) {
            int idx = tid + k * 256;
            kreg[k] = *(const half8_t*)(q16 + (size_t)(j0 + (idx >> 4)) * D + (idx & 15) * 8);
            int dr = idx >> 3, c8 = idx & 7;
            int base = j0 + (c8 >> 2) * 32 + (c8 & 3) * 4;
            vlo[k] = *(const half4_t*)(qT16 + (size_t)dr * T + base);
            vhi[k] = *(const half4_t*)(qT16 + (size_t)dr * T + base + 16);
        }
    }

    for (int it = 0; it < NITER; ++it) {
        int b = it & 1;
        // ---- commit regs (loaded last iter) to buf b ----
        for (int k = 0; k < 4; ++k) {
            int idx = tid + k * 256;
            *(half8_t*)&Kt[b][idx >> 4][(idx & 15) * 8] = kreg[k];
            half8_t v;
            v[0] = vlo[k][0]; v[1] = vlo[k][1]; v[2] = vlo[k][2]; v[3] = vlo[k][3];
            v[4] = vhi[k][0]; v[5] = vhi[k][1]; v[6] = vhi[k][2]; v[7] = vhi[k][3];
            *(half8_t*)&Vt[b][idx >> 3][(idx & 7) * 8] = v;
        }
        __syncthreads();

        // ---- issue next iteration's loads (land during compute + next commit) ----
        if (it + 1 < NITER) {
            int j0n = sp * JLEN + (it + 1) * BN;
            for (int k = 0; k < 4; ++k) {
                int idx = tid + k * 256;
                kreg[k] = *(const half8_t*)(q16 + (size_t)(j0n + (idx >> 4)) * D + (idx & 15) * 8);
                int dr = idx >> 3, c8 = idx & 7;
                int base = j0n + (c8 >> 2) * 32 + (c8 & 3) * 4;
                vlo[k] = *(const half4_t*)(qT16 + (size_t)dr * T + base);
                vhi[k] = *(const half4_t*)(qT16 + (size_t)dr * T + base + 16);
            }
        }

        // ---- St = K Qm^T : lane holds key=16jt+4q+r, query=16mt+l15 ----
        floatx4 St[2][4];
        for (int mt = 0; mt < 2; ++mt)
            for (int jt = 0; jt < 4; ++jt)
                for (int r = 0; r < 4; ++r) St[mt][jt][r] = 0.f;
        for (int ks = 0; ks < 4; ++ks)
            for (int jt = 0; jt < 4; ++jt) {
                half8_t a = *(const half8_t*)&Kt[b][jt * 16 + l15][ks * 32 + quad * 8];
                St[0][jt] = __builtin_amdgcn_mfma_f32_16x16x32_f16(a, qfrag[0][ks], St[0][jt], 0, 0, 0);
                St[1][jt] = __builtin_amdgcn_mfma_f32_16x16x32_f16(a, qfrag[1][ks], St[1][jt], 0, 0, 0);
            }

        // ---- per-key bias ----
        float4 bias[4];
        for (int jt = 0; jt < 4; ++jt)
            bias[jt] = *(const float4*)&qqs[it * 64 + jt * 16 + quad * 4];
        for (int mt = 0; mt < 2; ++mt) {
            St[mt][0][0] += bias[0].x; St[mt][0][1] += bias[0].y; St[mt][0][2] += bias[0].z; St[mt][0][3] += bias[0].w;
            St[mt][1][0] += bias[1].x; St[mt][1][1] += bias[1].y; St[mt][1][2] += bias[1].z; St[mt][1][3] += bias[1].w;
            St[mt][2][0] += bias[2].x; St[mt][2][1] += bias[2].y; St[mt][2][2] += bias[2].z; St[mt][2][3] += bias[2].w;
            St[mt][3][0] += bias[3].x; St[mt][3][1] += bias[3].y; St[mt][3][2] += bias[3].z; St[mt][3][3] += bias[3].w;
        }

        // ---- online softmax ----
        half4_t apv[2][4];
        float alpha[2];
        for (int mt = 0; mt < 2; ++mt) {
            float mx = St[mt][0][0];
            for (int jt = 0; jt < 4; ++jt)
                for (int r = 0; r < 4; ++r) mx = fmaxf(mx, St[mt][jt][r]);
            mx = fmaxf(mx, __shfl_xor(mx, 16));
            mx = fmaxf(mx, __shfl_xor(mx, 32));
            float mnew = fmaxf(m_run[mt], mx);
            alpha[mt] = __builtin_amdgcn_exp2f(m_run[mt] - mnew);
            m_run[mt] = mnew;
            float ps = 0.f;
            for (int jt = 0; jt < 4; ++jt) {
                float p0 = __builtin_amdgcn_exp2f(St[mt][jt][0] - mnew);
                float p1 = __builtin_amdgcn_exp2f(St[mt][jt][1] - mnew);
                float p2 = __builtin_amdgcn_exp2f(St[mt][jt][2] - mnew);
                float p3 = __builtin_amdgcn_exp2f(St[mt][jt][3] - mnew);
                ps += (p0 + p1) + (p2 + p3);
                apv[mt][jt][0] = (_Float16)p0;
                apv[mt][jt][1] = (_Float16)p1;
                apv[mt][jt][2] = (_Float16)p2;
                apv[mt][jt][3] = (_Float16)p3;
            }
            ps += __shfl_xor(ps, 16);
            ps += __shfl_xor(ps, 32);
            l_run[mt] = l_run[mt] * alpha[mt] + ps;
        }
        for (int mt = 0; mt < 2; ++mt) {
            float aT[4];
            for (int r = 0; r < 4; ++r)
                aT[r] = __shfl(alpha[mt], quad * 4 + r);
            for (int nt = 0; nt < 8; ++nt)
                for (int r = 0; r < 4; ++r) acc[mt][nt][r] *= aT[r];
        }

        // ---- O += P V via 16x16x16; b128 V reads, lo/hi half4 per jt pair ----
        for (int pr = 0; pr < 2; ++pr) {
            half8_t bb[8];
            for (int nt = 0; nt < 8; ++nt)
                bb[nt] = *(const half8_t*)&Vt[b][nt * 16 + l15][pr * 32 + quad * 8];
            for (int h = 0; h < 2; ++h) {
                int jt = pr * 2 + h;
                for (int nt = 0; nt < 8; ++nt) {
                    half4_t bv;
                    bv[0] = bb[nt][h * 4 + 0]; bv[1] = bb[nt][h * 4 + 1];
                    bv[2] = bb[nt][h * 4 + 2]; bv[3] = bb[nt][h * 4 + 3];
                    acc[0][nt] = __builtin_amdgcn_mfma_f32_16x16x16f16(apv[0][jt], bv, acc[0][nt], 0, 0, 0);
                    acc[1][nt] = __builtin_amdgcn_mfma_f32_16x16x16f16(apv[1][jt], bv, acc[1][nt], 0, 0, 0);
                }
            }
        }
    }

    // ---- finalize ----
    for (int mt = 0; mt < 2; ++mt) {
        if (quad == 0) {
            int iq = rbase + mt * 16 + l15;
            mpart[(size_t)sp * T + iq] = m_run[mt];
            lpart[(size_t)sp * T + iq] = l_run[mt];
        }
        int i = rbase + mt * 16 + quad * 4;
        for (int nt = 0; nt < 8; ++nt)
            for (int r = 0; r < 4; ++r)
                Opart[((size_t)sp * T + (i + r)) * D + nt * 16 + l15] = (_Float16)acc[mt][nt][r];
    }
}

// ---------------------------------------------------------------------------
// merge 8 f16 split partials -> U_A (fp32), linv[i] = 1/L_i.  grid 512, block 256
// ---------------------------------------------------------------------------
__global__ void merge_kernel(const _Float16* __restrict__ Opart, const float* __restrict__ mpart,
                             const float* __restrict__ lpart, float* __restrict__ U_A,
                             float* __restrict__ linv) {
    int t = threadIdx.x;
    int i = blockIdx.x * 16 + (t >> 4);
    int c = t & 15;
    float mp[NSPLIT], w[NSPLIT];
    float mstar = -INFINITY;
    for (int sp = 0; sp < NSPLIT; ++sp) {
        mp[sp] = mpart[(size_t)sp * T + i];
        mstar = fmaxf(mstar, mp[sp]);
    }
    float L = 0.f;
    for (int sp = 0; sp < NSPLIT; ++sp) {
        w[sp] = __builtin_amdgcn_exp2f(mp[sp] - mstar);
        L += lpart[(size_t)sp * T + i] * w[sp];
    }
    float invL = 1.0f / L;
    int d0 = c * 8;
    float u[8];
    for (int k = 0; k < 8; ++k) u[k] = 0.f;
    for (int sp = 0; sp < NSPLIT; ++sp) {
        half8_t o = *(const half8_t*)(Opart + ((size_t)sp * T + i) * D + d0);
        for (int k = 0; k < 8; ++k) u[k] += (float)o[k] * w[sp];
    }
    float4 s0 = make_float4(u[0] * invL, u[1] * invL, u[2] * invL, u[3] * invL);
    float4 s1 = make_float4(u[4] * invL, u[5] * invL, u[6] * invL, u[7] * invL);
    *(float4*)(U_A + (size_t)i * D + d0) = s0;
    *(float4*)(U_A + (size_t)i * D + d0 + 4) = s1;
    if (c == 0) linv[i] = invL;
}

// ---------------------------------------------------------------------------
// h partials then reduce.  grid 64 / grid 1
// ---------------------------------------------------------------------------
__global__ void hsum_part_kernel(const float* __restrict__ x, const float* __restrict__ linv,
                                 float* __restrict__ hpart) {
    const float* context = x;
    int t = threadIdx.x;
    int d = t & 127, g = t >> 7;
    int i0 = blockIdx.x * 128 + g * 64;
    float s = 0.f;
    for (int k = 0; k < 64; ++k)
        s += context[(size_t)(i0 + k) * D + d] * linv[i0 + k];
    hpart[(size_t)(blockIdx.x * 2 + g) * 128 + d] = s;
}

__global__ void hreduce_kernel(const float* __restrict__ hpart, float* __restrict__ h) {
    int d = threadIdx.x;  // 0..127
    float s = 0.f;
    for (int k = 0; k < 128; ++k) s += hpart[(size_t)k * 128 + d];
    h[d] = s;
}

// ---------------------------------------------------------------------------
// assemble G = [ctx, U_A, ctx*U_A, ctx*h]   grid 4096, block 256, float4/thread
// ---------------------------------------------------------------------------
__global__ void assemble_kernel(const float* __restrict__ x, const float* __restrict__ U_A,
                                const float* __restrict__ h, float* __restrict__ out) {
    const float* context = x;
    int gid = blockIdx.x * 256 + threadIdx.x;
    int base = gid * 4;
    int i = base >> 9;
    int c = base & 511;
    int seg = c >> 7, d = c & 127;
    float4 r;
    if (seg == 0) {
        r = *(const float4*)(context + (size_t)i * D + d);
    } else if (seg == 1) {
        r = *(const float4*)(U_A + (size_t)i * D + d);
    } else if (seg == 2) {
        float4 a = *(const float4*)(context + (size_t)i * D + d);
        float4 b = *(const float4*)(U_A + (size_t)i * D + d);
        r = make_float4(a.x * b.x, a.y * b.y, a.z * b.z, a.w * b.w);
    } else {
        float4 a = *(const float4*)(context + (size_t)i * D + d);
        float4 b = *(const float4*)(h + d);
        r = make_float4(a.x * b.x, a.y * b.y, a.z * b.z, a.w * b.w);
    }
    *(float4*)(out + base) = r;
}

// ---------------------------------------------------------------------------
extern "C" void kernel_launch(void* const* d_in, const int* in_sizes, int n_in,
                              void* d_out, int out_size, void* d_ws, size_t ws_size,
                              hipStream_t stream) {
    const float* x = (const float*)d_in[0];
    const float* kern = (const float*)d_in[1];
    float* out = (float*)d_out;

    char* w = (char*)d_ws;
    size_t off = 0;
    _Float16* q16  = (_Float16*)(w + off); off += (size_t)T * D * 2;   // 2 MB
    _Float16* qT16 = (_Float16*)(w + off); off += (size_t)T * D * 2;   // 2 MB
    _Float16* cm16 = (_Float16*)(w + off); off += (size_t)T * D * 2;   // 2 MB
    float* qq2   = (float*)(w + off); off += (size_t)T * 4;            // 32 KB
    float* mpart = (float*)(w + off); off += (size_t)NSPLIT * T * 4;   // 256 KB
    float* lpart = (float*)(w + off); off += (size_t)NSPLIT * T * 4;   // 256 KB
    float* U_A   = (float*)(w + off); off += (size_t)T * D * 4;        // 4 MB
    float* linv  = (float*)(w + off); off += (size_t)T * 4;            // 32 KB
    float* hpart = (float*)(w + off); off += (size_t)128 * 128 * 4;    // 64 KB
    float* h     = (float*)(w + off); off += (size_t)D * 4;

    // d_out doubles as f16 split-partial scratch: 8 * T * D * 2B = 16 MB
    _Float16* Opart = (_Float16*)d_out;

    prep_kernel<<<256, 256, 0, stream>>>(x, kern, q16, qT16, cm16, qq2);
    flash_kernel<<<512, 256, 0, stream>>>(q16, qT16, cm16, qq2, Opart, mpart, lpart);
    merge_kernel<<<512, 256, 0, stream>>>(Opart, mpart, lpart, U_A, linv);
    hsum_part_kernel<<<64, 256, 0, stream>>>(x, linv, hpart);
    hreduce_kernel<<<1, 128, 0, stream>>>(hpart, h);
    assemble_kernel<<<4096, 256, 0, stream>>>(x, U_A, h, out);
}